// Round 3
// baseline (2081.172 us; speedup 1.0000x reference)
//
#include <hip/hip_runtime.h>
#include <hip/hip_fp16.h>

typedef _Float16 half8 __attribute__((ext_vector_type(8)));
typedef float floatx4 __attribute__((ext_vector_type(4)));
typedef unsigned long long u64;

// workspace layout
#define HBUF_BYTES (2ull * 16 * 4 * 1024 * 2) // [parity][group][batch4][dim1024] f16 = 256 KB
#define CTL_BYTES  (32ull * 1024)             // reserved
#define XP_OFF     (HBUF_BYTES + CTL_BYTES)
#define XP_BYTES   (512ull * 64 * 1024 * 2)   // x_proj f16 [t][b][dim] = 64 MB

// bit14 of an f16 is the exponent MSB: set only for |v| >= 2. tanh outputs
// satisfy |v| <= 1, so bit14 is always 0 -> usable as a per-element epoch tag.
#define M8 0x4000400040004000ull

union pack4 { unsigned long long u; _Float16 h[4]; };
union frag16 { u64 u[2]; half8 h; };
union h16 { _Float16 h; unsigned short u; };

__device__ inline half8 cvt8(const float4 a, const float4 b) {
    half8 r;
    r[0] = (_Float16)a.x; r[1] = (_Float16)a.y; r[2] = (_Float16)a.z; r[3] = (_Float16)a.w;
    r[4] = (_Float16)b.x; r[5] = (_Float16)b.y; r[6] = (_Float16)b.z; r[7] = (_Float16)b.w;
    return r;
}

// ---------------------------------------------------------------------------
// Phase A: x_proj[t][b][n] = sum_k emb[src[b][t]][k] * W_xh[n][k] + b_xh[n]
// (unchanged — not the primary bottleneck)
// ---------------------------------------------------------------------------
__global__ __launch_bounds__(256) void xproj_kernel(
    const int* __restrict__ src, const float* __restrict__ emb,
    const float* __restrict__ Wxh, const float* __restrict__ bxh,
    _Float16* __restrict__ xp)
{
    __shared__ _Float16 As[128][40];
    __shared__ _Float16 Bs[128][40];

    const int tid  = threadIdx.x;
    const int lane = tid & 63;
    const int w    = tid >> 6;
    const int m15  = lane & 15;
    const int quad = lane >> 4;
    const int bid  = blockIdx.x;
    const int bn   = bid & 7;
    const int bm   = bid >> 3;
    const int m0   = bm * 128, n0 = bn * 128;
    const int wm   = w & 1, wn = w >> 1;

    const int  srow = tid >> 1;
    const int  scol = (tid & 1) * 16;
    const long arow = (long)src[m0 + srow] * 1024;
    const float* abase = emb + arow + scol;
    const float* bbase = Wxh + (long)(n0 + srow) * 1024 + scol;

    floatx4 zero4 = {0.f, 0.f, 0.f, 0.f};
    floatx4 acc[4][4];
#pragma unroll
    for (int mt = 0; mt < 4; mt++)
#pragma unroll
        for (int nt = 0; nt < 4; nt++) acc[mt][nt] = zero4;

    for (int k0 = 0; k0 < 1024; k0 += 32) {
        __syncthreads();
        float4 a0 = *(const float4*)(abase + k0);
        float4 a1 = *(const float4*)(abase + k0 + 4);
        float4 a2 = *(const float4*)(abase + k0 + 8);
        float4 a3 = *(const float4*)(abase + k0 + 12);
        float4 b0 = *(const float4*)(bbase + k0);
        float4 b1 = *(const float4*)(bbase + k0 + 4);
        float4 b2 = *(const float4*)(bbase + k0 + 8);
        float4 b3 = *(const float4*)(bbase + k0 + 12);
        *(half8*)&As[srow][scol]     = cvt8(a0, a1);
        *(half8*)&As[srow][scol + 8] = cvt8(a2, a3);
        *(half8*)&Bs[srow][scol]     = cvt8(b0, b1);
        *(half8*)&Bs[srow][scol + 8] = cvt8(b2, b3);
        __syncthreads();

        half8 af[4], bf[4];
#pragma unroll
        for (int mt = 0; mt < 4; mt++)
            af[mt] = *(const half8*)&As[wm * 64 + mt * 16 + m15][quad * 8];
#pragma unroll
        for (int nt = 0; nt < 4; nt++)
            bf[nt] = *(const half8*)&Bs[wn * 64 + nt * 16 + m15][quad * 8];
#pragma unroll
        for (int mt = 0; mt < 4; mt++)
#pragma unroll
            for (int nt = 0; nt < 4; nt++)
                acc[mt][nt] = __builtin_amdgcn_mfma_f32_16x16x32_f16(
                    af[mt], bf[nt], acc[mt][nt], 0, 0, 0);
    }

#pragma unroll
    for (int nt = 0; nt < 4; nt++) {
        const int n = n0 + wn * 64 + nt * 16 + m15;
        const float bias = bxh[n];
#pragma unroll
        for (int mt = 0; mt < 4; mt++) {
            const int mrow = m0 + wm * 64 + mt * 16 + quad * 4;
#pragma unroll
            for (int r = 0; r < 4; r++) {
                const int m = mrow + r;
                const int b = m >> 9;
                const int t = m & 511;
                xp[((long)t * 64 + b) * 1024 + n] = (_Float16)(acc[mt][nt][r] + bias);
            }
        }
    }
}

// ---------------------------------------------------------------------------
// Phase B: persistent recurrence, 256 WGs (1/CU).
// R7 STRUCTURE: zero-LDS-staging. h stored in global as plain [parity][group]
// [batch4][dim1024] f16, each element carrying the bit14 epoch tag (tanh =>
// |v|<=1 => bit14 free). The MFMA A-fragment IS the polled global load:
// lane (m15<4, quad) of wave w loads h[m15][w*256+kk*32+quad*8] as 2x8B
// relaxed agent-atomic loads, checks the 8 per-f16 tags, re-issues only
// stale words. Pad rows m15>=4 never touch memory (registers stay zero).
// This deletes the LDS transpose, its barrier, and all A ds_reads (the R6
// regression: 128KB/step LDS traffic + 8-way conflicts). K-split across
// waves (R5) restores 4 independent MFMA chains and minimal traffic
// (8 KB/CU/step). Cross-wave K-reduce via double-buffered cred -> ONE
// barrier/step:
//   cred[t&1] write@t -> barrier@t -> read@t; next write to same buffer is
//   @t+2, ordered by barrier@t+1. (Single-buffer read@t vs write@t+1 would
//   race.)
// Tag schedule T(s) = ((s>>1)^s)&1: per-slot alternation, memset zeros ==
// valid h_0 (parity 0, T(0)=0) and stale for h_1 (parity 1, T(1)=1).
// Enumeration s=0..7: T = 0,1,1,0,0,1,1,0 -> alternates within each parity.
// Back-pressure: producer stores h_{t+2} over h_t's slot only after
// validating h_{t+1}, which implies every WG passed barrier@t, which implies
// every wave everywhere finished its poll-loads of h_t. No fences anywhere.
// ---------------------------------------------------------------------------
__global__ __launch_bounds__(256, 1) void rnn_kernel(
    const float* __restrict__ Whh, const _Float16* __restrict__ xp,
    unsigned short* __restrict__ hb, float* __restrict__ out)
{
    __shared__ floatx4 cred[2][4][4][64];   // [buf][k-slice wave][ntile][lane]

    const int tid    = threadIdx.x;
    const int lane   = tid & 63;
    const int w      = tid >> 6;
    const int m15    = lane & 15;
    const int quad   = lane >> 4;
    const int wg     = blockIdx.x;
    const int g      = wg & 15;
    const int member = wg >> 4;
    const int b0     = g * 4;

    // W_hh fragments: wave w covers K slice [w*256, w*256+256), 4 n-tiles.
    // 32 x half8 = 128 VGPRs, reused for all 512 steps.
    half8 Wf[4][8];
#pragma unroll
    for (int nt = 0; nt < 4; nt++) {
        const float* wrow = Whh + (long)(member * 64 + nt * 16 + m15) * 1024
                                + w * 256 + quad * 8;
#pragma unroll
        for (int kk = 0; kk < 8; kk++) {
            float4 lo = *(const float4*)(wrow + kk * 32);
            float4 hi = *(const float4*)(wrow + kk * 32 + 4);
            Wf[nt][kk] = cvt8(lo, hi);
        }
    }

    const int dim = member * 64 + w * 16 + m15;
    float xv[4] = {0.f, 0.f, 0.f, 0.f};
    if (quad == 0) {
#pragma unroll
        for (int r = 0; r < 4; r++)
            xv[r] = (float)xp[((long)0 * 64 + b0 + r) * 1024 + dim];
    }

    // per-lane poll base (meaningful only for m15 < 4): f16 index within a
    // parity block = g*4096 + m15*1024 + w*256 + quad*8 (8-aligned -> /4 is
    // a valid u64 index; chunk kk adds 32 f16 = 8 u64).
    const unsigned myoff = (unsigned)(g * 4096 + m15 * 1024 + w * 256 + quad * 8);

    floatx4 zero4 = {0.f, 0.f, 0.f, 0.f};
    u64 av[8][2] = {};      // h_0 = zeros (valid: T(0)=0); m15>=4 lanes stay 0 forever

    for (int t = 0; t < 512; t++) {
        // (A) poll h_t directly into A-fragment registers (skip t=0: zeros)
        if (t > 0) {
            const u64* hp = (const u64*)(hb + (size_t)(t & 1) * 65536u) + (myoff >> 2);
            const u64 expM = (((t >> 1) ^ t) & 1) ? M8 : 0ull;
            unsigned done = (m15 < 4) ? 0u : 0xFFFFu;
            while (done != 0xFFFFu) {
#pragma unroll
                for (int kk = 0; kk < 8; kk++)
#pragma unroll
                    for (int hh = 0; hh < 2; hh++)
                        if (!(done & (1u << (kk * 2 + hh))))
                            av[kk][hh] = __hip_atomic_load(
                                hp + kk * 8 + hh, __ATOMIC_RELAXED,
                                __HIP_MEMORY_SCOPE_AGENT);
#pragma unroll
                for (int kk = 0; kk < 8; kk++)
#pragma unroll
                    for (int hh = 0; hh < 2; hh++)
                        if (!(done & (1u << (kk * 2 + hh))) &&
                            ((av[kk][hh] & M8) == expM))
                            done |= (1u << (kk * 2 + hh));
            }
        }

        // (B) strip tags, build A-fragments
        half8 a[8];
#pragma unroll
        for (int kk = 0; kk < 8; kk++) {
            frag16 f;
            f.u[0] = av[kk][0] & ~M8;
            f.u[1] = av[kk][1] & ~M8;
            a[kk] = f.h;
        }

        // (C) partial GEMM: 4 independent accumulator chains, depth 8
        floatx4 pacc[4];
#pragma unroll
        for (int nt = 0; nt < 4; nt++) pacc[nt] = zero4;
#pragma unroll
        for (int kk = 0; kk < 8; kk++)
#pragma unroll
            for (int nt = 0; nt < 4; nt++)
                pacc[nt] = __builtin_amdgcn_mfma_f32_16x16x32_f16(
                    a[kk], Wf[nt][kk], pacc[nt], 0, 0, 0);

        // (D) cross-wave K reduction, double-buffered, ONE barrier
        const int cb = t & 1;
#pragma unroll
        for (int nt = 0; nt < 4; nt++) cred[cb][w][nt][lane] = pacc[nt];
        __syncthreads();
        floatx4 dsum = cred[cb][0][w][lane];
#pragma unroll
        for (int ww = 1; ww < 4; ww++) dsum += cred[cb][ww][w][lane];

        // (E) epilogue: quad0 rows 0..3 are the real batches; tanh, tag,
        // 4 x 2B relaxed agent-atomic stores. The store IS the publication.
        if (quad == 0) {
            const unsigned short tag16 =
                (unsigned short)((((((t + 1) >> 1) ^ (t + 1)) & 1)) << 14);
            unsigned short* hs = hb + (size_t)((t + 1) & 1) * 65536u
                                    + (unsigned)(g * 4096 + dim);
#pragma unroll
            for (int r = 0; r < 4; r++) {
                float pre  = dsum[r] + xv[r];
                float e    = __expf(2.0f * pre);
                float hval = 1.0f - 2.0f / (e + 1.0f);   // tanh
                if (t == 511) {
                    out[(b0 + r) * 1024 + dim] = hval;
                } else {
                    h16 c; c.h = (_Float16)hval;
                    __hip_atomic_store(hs + r * 1024,
                                       (unsigned short)(c.u | tag16),
                                       __ATOMIC_RELAXED, __HIP_MEMORY_SCOPE_AGENT);
                }
            }
        }

        // (F) x_proj prefetch for t+1; drains while the next poll spins
        if (t < 511 && quad == 0) {
#pragma unroll
            for (int r = 0; r < 4; r++)
                xv[r] = (float)xp[((long)(t + 1) * 64 + b0 + r) * 1024 + dim];
        }
    }
}

extern "C" void kernel_launch(void* const* d_in, const int* in_sizes, int n_in,
                              void* d_out, int out_size, void* d_ws, size_t ws_size,
                              hipStream_t stream) {
    const int*   src = (const int*)d_in[0];
    const float* emb = (const float*)d_in[1];
    const float* Wxh = (const float*)d_in[2];
    const float* bxh = (const float*)d_in[3];
    const float* Whh = (const float*)d_in[4];
    float* out = (float*)d_out;

    char* ws = (char*)d_ws;
    unsigned short* hb = (unsigned short*)ws;
    _Float16* xp = (_Float16*)(ws + XP_OFF);

    // zero h buffers: parity 0 zeros ARE h_0 (tag 0 = T(0)); parity 1 zeros
    // are stale for h_1 (T(1)=1), so consumers block until real h_1 arrives.
    hipMemsetAsync(ws, 0, HBUF_BYTES, stream);

    hipLaunchKernelGGL(xproj_kernel, dim3(2048), dim3(256), 0, stream,
                       src, emb, Wxh, bxh, xp);

    hipLaunchKernelGGL(rnn_kernel, dim3(256), dim3(256), 0, stream,
                       Whh, xp, hb, out);
}

// Round 4
// 1176.901 us; speedup vs baseline: 1.7683x; 1.7683x over previous
//
#include <hip/hip_runtime.h>
#include <hip/hip_fp16.h>

typedef _Float16 half8 __attribute__((ext_vector_type(8)));
typedef float floatx4 __attribute__((ext_vector_type(4)));
typedef unsigned long long u64;

// workspace layout
#define HBUF_BYTES (2ull * 16 * 1024 * 8)   // [parity][group][dim] ulong (4 f16 batches) = 256 KB
#define CTL_BYTES  (32ull * 1024)           // reserved
#define XP_OFF     (HBUF_BYTES + CTL_BYTES)
#define XP_BYTES   (512ull * 64 * 1024 * 2) // x_proj f16 [t][b][dim] = 64 MB

#define TAG_BIT    (1ull << 14)             // bit14 of h[0]: always 0 for tanh outputs

union pack4 { unsigned long long u; _Float16 h[4]; };

__device__ inline half8 cvt8(const float4 a, const float4 b) {
    half8 r;
    r[0] = (_Float16)a.x; r[1] = (_Float16)a.y; r[2] = (_Float16)a.z; r[3] = (_Float16)a.w;
    r[4] = (_Float16)b.x; r[5] = (_Float16)b.y; r[6] = (_Float16)b.z; r[7] = (_Float16)b.w;
    return r;
}

// ---------------------------------------------------------------------------
// Phase A: x_proj = emb[src] @ W_xh^T + b_xh.
// R8: register-prefetch pipeline — next k-chunk's 8 global loads issue right
// after the stage barrier and drain under the MFMA phase.
// ---------------------------------------------------------------------------
__global__ __launch_bounds__(256) void xproj_kernel(
    const int* __restrict__ src, const float* __restrict__ emb,
    const float* __restrict__ Wxh, const float* __restrict__ bxh,
    _Float16* __restrict__ xp)
{
    __shared__ _Float16 As[128][40];
    __shared__ _Float16 Bs[128][40];

    const int tid  = threadIdx.x;
    const int lane = tid & 63;
    const int w    = tid >> 6;
    const int m15  = lane & 15;
    const int quad = lane >> 4;
    const int bid  = blockIdx.x;
    const int bn   = bid & 7;
    const int bm   = bid >> 3;
    const int m0   = bm * 128, n0 = bn * 128;
    const int wm   = w & 1, wn = w >> 1;

    const int  srow = tid >> 1;
    const int  scol = (tid & 1) * 16;
    const long arow = (long)src[m0 + srow] * 1024;
    const float* abase = emb + arow + scol;
    const float* bbase = Wxh + (long)(n0 + srow) * 1024 + scol;

    floatx4 zero4 = {0.f, 0.f, 0.f, 0.f};
    floatx4 acc[4][4];
#pragma unroll
    for (int mt = 0; mt < 4; mt++)
#pragma unroll
        for (int nt = 0; nt < 4; nt++) acc[mt][nt] = zero4;

    // preload k-chunk 0 into registers
    float4 a0 = *(const float4*)(abase);
    float4 a1 = *(const float4*)(abase + 4);
    float4 a2 = *(const float4*)(abase + 8);
    float4 a3 = *(const float4*)(abase + 12);
    float4 b0 = *(const float4*)(bbase);
    float4 b1 = *(const float4*)(bbase + 4);
    float4 b2 = *(const float4*)(bbase + 8);
    float4 b3 = *(const float4*)(bbase + 12);

    for (int k0 = 0; k0 < 1024; k0 += 32) {
        // stage current registers to LDS
        *(half8*)&As[srow][scol]     = cvt8(a0, a1);
        *(half8*)&As[srow][scol + 8] = cvt8(a2, a3);
        *(half8*)&Bs[srow][scol]     = cvt8(b0, b1);
        *(half8*)&Bs[srow][scol + 8] = cvt8(b2, b3);
        __syncthreads();

        // issue next chunk's loads early; they drain under the MFMAs
        if (k0 + 32 < 1024) {
            const int kn = k0 + 32;
            a0 = *(const float4*)(abase + kn);
            a1 = *(const float4*)(abase + kn + 4);
            a2 = *(const float4*)(abase + kn + 8);
            a3 = *(const float4*)(abase + kn + 12);
            b0 = *(const float4*)(bbase + kn);
            b1 = *(const float4*)(bbase + kn + 4);
            b2 = *(const float4*)(bbase + kn + 8);
            b3 = *(const float4*)(bbase + kn + 12);
        }

        half8 af[4], bf[4];
#pragma unroll
        for (int mt = 0; mt < 4; mt++)
            af[mt] = *(const half8*)&As[wm * 64 + mt * 16 + m15][quad * 8];
#pragma unroll
        for (int nt = 0; nt < 4; nt++)
            bf[nt] = *(const half8*)&Bs[wn * 64 + nt * 16 + m15][quad * 8];
#pragma unroll
        for (int mt = 0; mt < 4; mt++)
#pragma unroll
            for (int nt = 0; nt < 4; nt++)
                acc[mt][nt] = __builtin_amdgcn_mfma_f32_16x16x32_f16(
                    af[mt], bf[nt], acc[mt][nt], 0, 0, 0);

        __syncthreads();   // protect next stage write (WAR vs this iter's reads)
    }

#pragma unroll
    for (int nt = 0; nt < 4; nt++) {
        const int n = n0 + wn * 64 + nt * 16 + m15;
        const float bias = bxh[n];
#pragma unroll
        for (int mt = 0; mt < 4; mt++) {
            const int mrow = m0 + wm * 64 + mt * 16 + quad * 4;
#pragma unroll
            for (int r = 0; r < 4; r++) {
                const int m = mrow + r;
                const int b = m >> 9;
                const int t = m & 511;
                xp[((long)t * 64 + b) * 1024 + n] = (_Float16)(acc[mt][nt][r] + bias);
            }
        }
    }
}

// ---------------------------------------------------------------------------
// Phase B: persistent recurrence, 256 WGs (1/CU).
// R8 = R5 comm layout (packed [parity][group][dim] u64, one 8B store per
// producer lane, coalesced poll) + WAVE-LOCAL staging:
//   wave w polls exactly its own K-slice words [256w, 256w+256) (lane+64i,
//   still 512B/instruction coalesced) and writes only hstage columns it
//   alone reads -> the hstage write->read dependency is wave-local (program
//   order, lgkmcnt), so barrier #1 is DELETED and no wave waits on the
//   slowest poller before its MFMAs. Single hstage buffer is safe: wave w's
//   writes@t follow its own reads@t-1 in program order; no other wave ever
//   touches those columns. Rows 4..15 stay zero (M-pad).
// cred is double-buffered so its barrier is the ONLY barrier per step:
//   write cred[t&1] -> barrier@t -> read cred[t&1]; next write to this
//   buffer is @t+2, ordered by barrier@t+1.
// Tag scheme unchanged (R5): tag(h_s) = ((s+1)>>1)&1 in bit14 of h[0];
// memset zeros = valid h_0 (parity 0), stale for h_1 (parity 1).
// Back-pressure unchanged: producer stores h_{t+1} only after validating
// h_t, which implies every member finished polling h_{t-1} (the slot being
// overwritten). No fences anywhere.
// ---------------------------------------------------------------------------
__global__ __launch_bounds__(256, 1) void rnn_kernel(
    const float* __restrict__ Whh, const _Float16* __restrict__ xp,
    unsigned long long* __restrict__ hb, float* __restrict__ out)
{
    __shared__ _Float16 hstage[16][1032];       // rows 4..15 stay zero (M-pad)
    __shared__ floatx4  cred[2][4][4][64];      // [buf][k-slice wave][ntile][lane]

    const int tid    = threadIdx.x;
    const int lane   = tid & 63;
    const int w      = tid >> 6;
    const int m15    = lane & 15;
    const int quad   = lane >> 4;
    const int wg     = blockIdx.x;
    const int g      = wg & 15;
    const int member = wg >> 4;
    const int b0     = g * 4;

    for (int i = tid; i < 16 * 1032; i += 256) ((_Float16*)hstage)[i] = (_Float16)0.f;

    // W_hh slice -> 128 VGPRs (f16), reused for all 512 steps
    half8 Wf[4][8];
#pragma unroll
    for (int nt = 0; nt < 4; nt++) {
        const float* wrow = Whh + (long)(member * 64 + nt * 16 + m15) * 1024
                                + w * 256 + quad * 8;
#pragma unroll
        for (int kk = 0; kk < 8; kk++) {
            float4 lo = *(const float4*)(wrow + kk * 32);
            float4 hi = *(const float4*)(wrow + kk * 32 + 4);
            Wf[nt][kk] = cvt8(lo, hi);
        }
    }
    __syncthreads();    // hstage zero-fill (cross-wave) visible before step 0

    const int dim = member * 64 + w * 16 + m15;
    float xv[4] = {0.f, 0.f, 0.f, 0.f};
    if (quad == 0) {
#pragma unroll
        for (int r = 0; r < 4; r++)
            xv[r] = (float)xp[((long)0 * 64 + b0 + r) * 1024 + dim];
    }

    floatx4 zero4 = {0.f, 0.f, 0.f, 0.f};

    for (int t = 0; t < 512; t++) {
        // (A) poll THIS WAVE's K-slice of h_t (coalesced: 64 consecutive
        // u64 per load instruction), tags in the data words themselves.
        const u64* hcu = hb + (size_t)(t & 1) * 16384 + (size_t)g * 1024
                            + (size_t)w * 256;
        const u64 exp_tag = (u64)(((t + 1) >> 1) & 1) << 14;

        u64 v[4];
        for (;;) {
            bool ok = true;
#pragma unroll
            for (int i = 0; i < 4; i++)
                v[i] = __hip_atomic_load(hcu + lane + 64 * i, __ATOMIC_RELAXED,
                                         __HIP_MEMORY_SCOPE_AGENT);
#pragma unroll
            for (int i = 0; i < 4; i++)
                ok &= ((v[i] & TAG_BIT) == exp_tag);
            if (ok) break;
        }

        // (B) scatter into OWN columns of hstage (wave-local, no barrier)
#pragma unroll
        for (int i = 0; i < 4; i++) {
            pack4 p; p.u = v[i] & ~TAG_BIT;
            const int d = w * 256 + lane + 64 * i;
#pragma unroll
            for (int b = 0; b < 4; b++) hstage[b][d] = p.h[b];
        }

        // (C) partial GEMM over this wave's K-slice, 4 n-tiles (reads only
        // columns this wave just wrote; lgkmcnt ordering is intra-wave)
        floatx4 pacc[4];
#pragma unroll
        for (int nt = 0; nt < 4; nt++) pacc[nt] = zero4;
#pragma unroll
        for (int kk = 0; kk < 8; kk++) {
            half8 a = *(const half8*)&hstage[m15][w * 256 + kk * 32 + quad * 8];
#pragma unroll
            for (int nt = 0; nt < 4; nt++)
                pacc[nt] = __builtin_amdgcn_mfma_f32_16x16x32_f16(
                    a, Wf[nt][kk], pacc[nt], 0, 0, 0);
        }

        // (D) cross-wave K reduction, double-buffered, ONE barrier per step
        const int cb = t & 1;
#pragma unroll
        for (int nt = 0; nt < 4; nt++) cred[cb][w][nt][lane] = pacc[nt];
        __syncthreads();
        floatx4 dsum = cred[cb][0][w][lane];
#pragma unroll
        for (int ww = 1; ww < 4; ww++) dsum += cred[cb][ww][w][lane];

        // (E) epilogue: quad 0 rows 0..3 are the real batches; tanh, tag,
        // one 8B relaxed agent-atomic store. The store IS the publication.
        if (quad == 0) {
            pack4 p;
#pragma unroll
            for (int r = 0; r < 4; r++) {
                float pre  = dsum[r] + xv[r];
                float e    = __expf(2.0f * pre);
                float hval = 1.0f - 2.0f / (e + 1.0f);   // tanh
                p.h[r] = (_Float16)hval;
                if (t == 511) out[(b0 + r) * 1024 + dim] = hval;
            }
            if (t < 511) {
                unsigned long long* hnu =
                    hb + (size_t)((t + 1) & 1) * 16384 + (size_t)g * 1024;
                const u64 st_tag = (u64)(((t + 2) >> 1) & 1) << 14;
                __hip_atomic_store(hnu + dim, p.u | st_tag, __ATOMIC_RELAXED,
                                   __HIP_MEMORY_SCOPE_AGENT);
            }
        }

        // (F) x_proj prefetch for t+1; drains while the next poll spins
        if (t < 511 && quad == 0) {
#pragma unroll
            for (int r = 0; r < 4; r++)
                xv[r] = (float)xp[((long)(t + 1) * 64 + b0 + r) * 1024 + dim];
        }
    }
}

extern "C" void kernel_launch(void* const* d_in, const int* in_sizes, int n_in,
                              void* d_out, int out_size, void* d_ws, size_t ws_size,
                              hipStream_t stream) {
    const int*   src = (const int*)d_in[0];
    const float* emb = (const float*)d_in[1];
    const float* Wxh = (const float*)d_in[2];
    const float* bxh = (const float*)d_in[3];
    const float* Whh = (const float*)d_in[4];
    float* out = (float*)d_out;

    char* ws = (char*)d_ws;
    unsigned long long* hb = (unsigned long long*)ws;
    _Float16* xp = (_Float16*)(ws + XP_OFF);

    // zero h buffers: parity-0 zeros ARE h_0 (tag 0 = expected); parity-1
    // zeros are stale for h_1, so consumers block until real h_1 arrives.
    hipMemsetAsync(ws, 0, HBUF_BYTES, stream);

    hipLaunchKernelGGL(xproj_kernel, dim3(2048), dim3(256), 0, stream,
                       src, emb, Wxh, bxh, xp);

    hipLaunchKernelGGL(rnn_kernel, dim3(256), dim3(256), 0, stream,
                       Whh, xp, hb, out);
}